// Round 1
// baseline (274.088 us; speedup 1.0000x reference)
//
#include <hip/hip_runtime.h>
#include <hip/hip_bf16.h>
#include <stdint.h>

// KANLinear fused as one bf16 MFMA GEMM: C = A @ W^T
//   A (B x 2304): cols [0,256)   = silu(x[b,i])
//                 cols 256+i*8+c = cubic bspline basis_c(x[b,i])
//   W (256 x 2304): base_weight | spline_weight*scaler   (built in d_ws, bf16)
// B=32768, IN=OUT=256, K=2304. Grid uniform: h=0.4, grid[0]=-2.2.

#define IN_F 256
#define OUT_F 256
#define NCOEF 8
#define KDIM (IN_F + IN_F * NCOEF) /* 2304 */
#define BK 64
#define NCHUNK (KDIM / BK) /* 36 */
#define LDSS 72            /* row stride in bf16: 144B = 36 banks -> 2-way (free) conflicts */

typedef float f32x4 __attribute__((ext_vector_type(4)));
typedef short bf16x8 __attribute__((ext_vector_type(8)));

__device__ __forceinline__ uint32_t f2bf(float f) {
    union { float f; uint32_t u; } c; c.f = f;
    uint32_t u = c.u;
    return (u + 0x7FFFu + ((u >> 16) & 1u)) >> 16;   // RNE
}

__device__ __forceinline__ float silu_f(float v) {
    return v / (1.0f + __expf(-v));
}

// ---------------- kernel 1: combined bf16 weight (OUT_F x KDIM) ----------------
__global__ void build_w(const float* __restrict__ bw, const float* __restrict__ sw,
                        const float* __restrict__ ss, unsigned short* __restrict__ Wc) {
    const int o = blockIdx.x;
    const int i = threadIdx.x;
    // base part: k = i
    Wc[o * KDIM + i] = (unsigned short)f2bf(bw[o * IN_F + i]);
    // spline part: k = 256 + i*8 + c, scaled by spline_scaler
    const float scal = ss[o * IN_F + i];
    const float4* swv = reinterpret_cast<const float4*>(sw + (size_t)(o * IN_F + i) * NCOEF);
    float4 s0 = swv[0], s1 = swv[1];
    uint4 wv;
    wv.x = f2bf(s0.x * scal) | (f2bf(s0.y * scal) << 16);
    wv.y = f2bf(s0.z * scal) | (f2bf(s0.w * scal) << 16);
    wv.z = f2bf(s1.x * scal) | (f2bf(s1.y * scal) << 16);
    wv.w = f2bf(s1.z * scal) | (f2bf(s1.w * scal) << 16);
    *reinterpret_cast<uint4*>(Wc + o * KDIM + IN_F + i * NCOEF) = wv;
}

// ---------------- kernel 2: fused GEMM ----------------
__launch_bounds__(256, 2)
__global__ void kan_gemm(const float* __restrict__ x, const unsigned short* __restrict__ Wc,
                         float* __restrict__ out) {
    __shared__ __align__(16) unsigned short As[128 * LDSS];
    __shared__ __align__(16) unsigned short Bs[128 * LDSS];

    const int bid = blockIdx.x;
    const int mtile = bid >> 1;
    const int ntile = bid & 1;
    const int row0 = mtile * 128;
    const int col0 = ntile * 128;
    const int tid = threadIdx.x;
    const int lane = tid & 63;
    const int wv = tid >> 6;
    const int wm = wv >> 1, wn = wv & 1;
    const int l15 = lane & 15;
    const int q = lane >> 4;

    const int r_st = tid >> 1;  // staging row 0..127
    const int half = tid & 1;

    f32x4 acc[4][4] = {};

    for (int kc = 0; kc < NCHUNK; ++kc) {
        // ---- stage Bs: rows = output features, contiguous in k ----
        {
            const int rgrp = tid >> 3;  // 0..31
            const int seg = tid & 7;    // 16B segment within the 128B row-chunk
            const unsigned short* src = Wc + kc * BK + seg * 8;
#pragma unroll
            for (int rr = 0; rr < 4; ++rr) {
                int r = rgrp + rr * 32;
                uint4 v = *reinterpret_cast<const uint4*>(src + (size_t)(col0 + r) * KDIM);
                *reinterpret_cast<uint4*>(&Bs[r * LDSS + seg * 8]) = v;
            }
        }
        // ---- stage As: computed on the fly from x ----
        if (kc < 4) {
            // silu region: cols kc*64 .. +64 of x
            const float* xs = x + (size_t)(row0 + r_st) * IN_F + kc * 64 + half * 32;
            const float4* xv4 = reinterpret_cast<const float4*>(xs);
#pragma unroll
            for (int qq = 0; qq < 4; ++qq) {
                float4 a = xv4[qq * 2];
                float4 b = xv4[qq * 2 + 1];
                uint4 wvv;
                wvv.x = f2bf(silu_f(a.x)) | (f2bf(silu_f(a.y)) << 16);
                wvv.y = f2bf(silu_f(a.z)) | (f2bf(silu_f(a.w)) << 16);
                wvv.z = f2bf(silu_f(b.x)) | (f2bf(silu_f(b.y)) << 16);
                wvv.w = f2bf(silu_f(b.z)) | (f2bf(silu_f(b.w)) << 16);
                *reinterpret_cast<uint4*>(&As[r_st * LDSS + half * 32 + qq * 8]) = wvv;
            }
        } else {
            // basis region: inputs i0..i0+7, 8 coefs each
            const int i0 = (kc - 4) * 8;
            float4 xv = *reinterpret_cast<const float4*>(
                x + (size_t)(row0 + r_st) * IN_F + i0 + half * 4);
            float xs4[4] = {xv.x, xv.y, xv.z, xv.w};
#pragma unroll
            for (int xi = 0; xi < 4; ++xi) {
                float xx = xs4[xi];
                float u = (xx + 2.2f) * 2.5f;   // (x - grid[0]) / h
                float jf = floorf(u);
                float t = u - jf;
                int j0 = (int)jf;
                float t2 = t * t, t3 = t2 * t;
                float p3 = t3 * (1.0f / 6.0f);                                   // j = j0
                float p2 = -0.5f * t3 + 0.5f * t2 + 0.5f * t + (1.0f / 6.0f);    // j = j0-1
                float p1 = 0.5f * t3 - t2 + (2.0f / 3.0f);                       // j = j0-2
                float omt = 1.0f - t;
                float p0 = omt * omt * omt * (1.0f / 6.0f);                      // j = j0-3
                uint32_t h[8];
#pragma unroll
                for (int j = 0; j < 8; ++j) {
                    int s = j0 - j;
                    float v = (s == 0) ? p3 : (s == 1) ? p2 : (s == 2) ? p1 : (s == 3) ? p0 : 0.0f;
                    h[j] = f2bf(v);
                }
                uint4 wvv;
                wvv.x = h[0] | (h[1] << 16);
                wvv.y = h[2] | (h[3] << 16);
                wvv.z = h[4] | (h[5] << 16);
                wvv.w = h[6] | (h[7] << 16);
                *reinterpret_cast<uint4*>(&As[r_st * LDSS + half * 32 + xi * 8]) = wvv;
            }
        }
        __syncthreads();

        // ---- MFMA over this K-chunk ----
#pragma unroll
        for (int kk = 0; kk < BK; kk += 32) {
            bf16x8 af[4], bfv[4];
#pragma unroll
            for (int mt = 0; mt < 4; ++mt)
                af[mt] = *reinterpret_cast<const bf16x8*>(
                    &As[(wm * 64 + mt * 16 + l15) * LDSS + kk + q * 8]);
#pragma unroll
            for (int nt = 0; nt < 4; ++nt)
                bfv[nt] = *reinterpret_cast<const bf16x8*>(
                    &Bs[(wn * 64 + nt * 16 + l15) * LDSS + kk + q * 8]);
#pragma unroll
            for (int mt = 0; mt < 4; ++mt)
#pragma unroll
                for (int nt = 0; nt < 4; ++nt)
                    acc[mt][nt] = __builtin_amdgcn_mfma_f32_16x16x32_bf16(
                        af[mt], bfv[nt], acc[mt][nt], 0, 0, 0);
        }
        __syncthreads();
    }

    // ---- epilogue: C/D layout col = lane&15, row = (lane>>4)*4 + reg ----
#pragma unroll
    for (int mt = 0; mt < 4; ++mt) {
        int row = row0 + wm * 64 + mt * 16 + q * 4;
#pragma unroll
        for (int nt = 0; nt < 4; ++nt) {
            int col = col0 + wn * 64 + nt * 16 + l15;
#pragma unroll
            for (int r = 0; r < 4; ++r)
                out[(size_t)(row + r) * OUT_F + col] = acc[mt][nt][r];
        }
    }
}

extern "C" void kernel_launch(void* const* d_in, const int* in_sizes, int n_in,
                              void* d_out, int out_size, void* d_ws, size_t ws_size,
                              hipStream_t stream) {
    const float* x  = (const float*)d_in[0];
    const float* bw = (const float*)d_in[1];
    const float* sw = (const float*)d_in[2];
    const float* ss = (const float*)d_in[3];
    unsigned short* Wc = (unsigned short*)d_ws;  // 256*2304*2 = 1.18 MB

    build_w<<<dim3(OUT_F), dim3(IN_F), 0, stream>>>(bw, sw, ss, Wc);

    const int B_ROWS = in_sizes[0] / IN_F;            // 32768
    dim3 grid(B_ROWS / 128 * 2);                      // 256 M-tiles x 2 N-tiles = 512
    kan_gemm<<<grid, dim3(256), 0, stream>>>(x, Wc, (float*)d_out);
}

// Round 2
// 161.813 us; speedup vs baseline: 1.6939x; 1.6939x over previous
//
#include <hip/hip_runtime.h>
#include <hip/hip_bf16.h>
#include <stdint.h>

// KANLinear as: (1) build_w: combined bf16 weight W (256 x 2304) in ws
//               (2) expand:  A (32768 x 2304 bf16) = [silu(x) | bspline bases] in ws
//               (3) kan_gemm2: C = A @ W^T via MFMA + global_load_lds staging
// Fallback to the fused single-pass kernel if ws_size is too small.

#define IN_F 256
#define OUT_F 256
#define NCOEF 8
#define KDIM (IN_F + IN_F * NCOEF) /* 2304 */
#define BK 64
#define NCHUNK (KDIM / BK) /* 36 */
#define LDSS 72            /* fused-kernel LDS row stride */

#define WC_BYTES ((size_t)OUT_F * KDIM * 2)            /* 1,179,648 */
#define AEXP_BYTES ((size_t)32768 * KDIM * 2)          /* 150,994,944 */

#define AS1 __attribute__((address_space(1)))
#define AS3 __attribute__((address_space(3)))

typedef float f32x4 __attribute__((ext_vector_type(4)));
typedef short bf16x8 __attribute__((ext_vector_type(8)));

__device__ __forceinline__ uint32_t f2bf(float f) {
    union { float f; uint32_t u; } c; c.f = f;
    uint32_t u = c.u;
    return (u + 0x7FFFu + ((u >> 16) & 1u)) >> 16;   // RNE
}

__device__ __forceinline__ float silu_f(float v) {
    return v / (1.0f + __expf(-v));
}

// ---------------- kernel 1: combined bf16 weight (OUT_F x KDIM) ----------------
__global__ void build_w(const float* __restrict__ bw, const float* __restrict__ sw,
                        const float* __restrict__ ss, unsigned short* __restrict__ Wc) {
    const int o = blockIdx.x;
    const int i = threadIdx.x;
    Wc[o * KDIM + i] = (unsigned short)f2bf(bw[o * IN_F + i]);
    const float scal = ss[o * IN_F + i];
    const float4* swv = reinterpret_cast<const float4*>(sw + (size_t)(o * IN_F + i) * NCOEF);
    float4 s0 = swv[0], s1 = swv[1];
    uint4 wv;
    wv.x = f2bf(s0.x * scal) | (f2bf(s0.y * scal) << 16);
    wv.y = f2bf(s0.z * scal) | (f2bf(s0.w * scal) << 16);
    wv.z = f2bf(s1.x * scal) | (f2bf(s1.y * scal) << 16);
    wv.w = f2bf(s1.z * scal) | (f2bf(s1.w * scal) << 16);
    *reinterpret_cast<uint4*>(Wc + o * KDIM + IN_F + i * NCOEF) = wv;
}

// ---------------- kernel 2: expand A = [silu | bases] to bf16 ----------------
// one block per batch row; thread i handles x[b,i]
__global__ void expand_a(const float* __restrict__ x, unsigned short* __restrict__ A) {
    const int b = blockIdx.x;
    const int i = threadIdx.x;
    const float xx = x[(size_t)b * IN_F + i];

    // silu -> col i
    A[(size_t)b * KDIM + i] = (unsigned short)f2bf(silu_f(xx));

    // cubic uniform bspline: 4 nonzero bases placed by 128-bit shift
    float u = (xx + 2.2f) * 2.5f;          // (x - grid[0]) / h
    float jf = floorf(u);
    float t = u - jf;
    int j0 = (int)jf;
    float t2 = t * t, t3 = t2 * t;
    float p3 = t3 * (1.0f / 6.0f);                                // j = j0
    float p2 = -0.5f * t3 + 0.5f * t2 + 0.5f * t + (1.0f / 6.0f); // j = j0-1
    float p1 = 0.5f * t3 - t2 + (2.0f / 3.0f);                    // j = j0-2
    float omt = 1.0f - t;
    float p0 = omt * omt * omt * (1.0f / 6.0f);                   // j = j0-3

    uint64_t packed = (uint64_t)f2bf(p0) | ((uint64_t)f2bf(p1) << 16) |
                      ((uint64_t)f2bf(p2) << 32) | ((uint64_t)f2bf(p3) << 48);
    unsigned __int128 v = 0;
    if ((unsigned)j0 <= 10u) {
        int sh = j0 * 16 - 48;
        unsigned __int128 p = (unsigned __int128)packed;
        v = (sh >= 0) ? (p << sh) : (p >> (-sh));
    }
    uint4 res;
    res.x = (uint32_t)v;
    res.y = (uint32_t)(v >> 32);
    res.z = (uint32_t)(v >> 64);
    res.w = (uint32_t)(v >> 96);
    *reinterpret_cast<uint4*>(A + (size_t)b * KDIM + IN_F + i * NCOEF) = res;
}

// ---------------- kernel 3: pure MFMA GEMM, global_load_lds staging ----------------
// C[m,n] = sum_k A[m,k] * W[n,k];  128x128 tile, BK=64, 4 waves (2x2), 4x4 MFMA each
// LDS layout (per tile): addr(row, g) = row*128B + ((g ^ (row&7))*16B), g = k/8
__launch_bounds__(256, 2)
__global__ void kan_gemm2(const unsigned short* __restrict__ A,
                          const unsigned short* __restrict__ Wc,
                          float* __restrict__ out) {
    __shared__ __align__(16) unsigned short As[128 * 64];
    __shared__ __align__(16) unsigned short Bs[128 * 64];

    const int bid = blockIdx.x;
    const int mtile = bid >> 1;
    const int ntile = bid & 1;
    const int row0 = mtile * 128;
    const int col0 = ntile * 128;
    const int tid = threadIdx.x;
    const int lane = tid & 63;
    const int wv = tid >> 6;           // wave id, uniform
    const int wm = wv >> 1, wn = wv & 1;
    const int l15 = lane & 15;
    const int q = lane >> 4;

    // staging lane mapping: 8 rows x 8 swizzled 16B segments per instruction
    const int sr = lane >> 3;                  // 0..7
    const int sg = (lane & 7) ^ (sr & 7);      // swizzled k-segment

    f32x4 acc[4][4] = {};

    for (int kc = 0; kc < NCHUNK; ++kc) {
#pragma unroll
        for (int j = 0; j < 4; ++j) {
            const unsigned short* gp =
                A + (size_t)(row0 + wv * 32 + j * 8 + sr) * KDIM + kc * BK + sg * 8;
            __builtin_amdgcn_global_load_lds((const AS1 void*)gp,
                                             (AS3 void*)&As[(wv * 32 + j * 8) * 64],
                                             16, 0, 0);
        }
#pragma unroll
        for (int j = 0; j < 4; ++j) {
            const unsigned short* gp =
                Wc + (size_t)(col0 + wv * 32 + j * 8 + sr) * KDIM + kc * BK + sg * 8;
            __builtin_amdgcn_global_load_lds((const AS1 void*)gp,
                                             (AS3 void*)&Bs[(wv * 32 + j * 8) * 64],
                                             16, 0, 0);
        }
        __syncthreads();

#pragma unroll
        for (int kk = 0; kk < BK; kk += 32) {
            bf16x8 af[4], bfv[4];
            const int g0 = (kk >> 3) + q;
#pragma unroll
            for (int mt = 0; mt < 4; ++mt) {
                int r = wm * 64 + mt * 16 + l15;
                af[mt] = *reinterpret_cast<const bf16x8*>(
                    &As[r * 64 + ((g0 ^ (r & 7)) << 3)]);
            }
#pragma unroll
            for (int nt = 0; nt < 4; ++nt) {
                int r = wn * 64 + nt * 16 + l15;
                bfv[nt] = *reinterpret_cast<const bf16x8*>(
                    &Bs[r * 64 + ((g0 ^ (r & 7)) << 3)]);
            }
#pragma unroll
            for (int mt = 0; mt < 4; ++mt)
#pragma unroll
                for (int nt = 0; nt < 4; ++nt)
                    acc[mt][nt] = __builtin_amdgcn_mfma_f32_16x16x32_bf16(
                        af[mt], bfv[nt], acc[mt][nt], 0, 0, 0);
        }
        __syncthreads();
    }

    // epilogue: C/D layout col = lane&15, row = (lane>>4)*4 + reg
#pragma unroll
    for (int mt = 0; mt < 4; ++mt) {
        int row = row0 + wm * 64 + mt * 16 + q * 4;
#pragma unroll
        for (int nt = 0; nt < 4; ++nt) {
            int col = col0 + wn * 64 + nt * 16 + l15;
#pragma unroll
            for (int r = 0; r < 4; ++r)
                out[(size_t)(row + r) * OUT_F + col] = acc[mt][nt][r];
        }
    }
}

// ---------------- fallback: fused single-pass kernel (round-1, verified) ----------------
__launch_bounds__(256, 2)
__global__ void kan_gemm(const float* __restrict__ x, const unsigned short* __restrict__ Wc,
                         float* __restrict__ out) {
    __shared__ __align__(16) unsigned short As[128 * LDSS];
    __shared__ __align__(16) unsigned short Bs[128 * LDSS];

    const int bid = blockIdx.x;
    const int mtile = bid >> 1;
    const int ntile = bid & 1;
    const int row0 = mtile * 128;
    const int col0 = ntile * 128;
    const int tid = threadIdx.x;
    const int lane = tid & 63;
    const int wv = tid >> 6;
    const int wm = wv >> 1, wn = wv & 1;
    const int l15 = lane & 15;
    const int q = lane >> 4;

    const int r_st = tid >> 1;
    const int half = tid & 1;

    f32x4 acc[4][4] = {};

    for (int kc = 0; kc < NCHUNK; ++kc) {
        {
            const int rgrp = tid >> 3;
            const int seg = tid & 7;
            const unsigned short* src = Wc + kc * BK + seg * 8;
#pragma unroll
            for (int rr = 0; rr < 4; ++rr) {
                int r = rgrp + rr * 32;
                uint4 v = *reinterpret_cast<const uint4*>(src + (size_t)(col0 + r) * KDIM);
                *reinterpret_cast<uint4*>(&Bs[r * LDSS + seg * 8]) = v;
            }
        }
        if (kc < 4) {
            const float* xs = x + (size_t)(row0 + r_st) * IN_F + kc * 64 + half * 32;
            const float4* xv4 = reinterpret_cast<const float4*>(xs);
#pragma unroll
            for (int qq = 0; qq < 4; ++qq) {
                float4 a = xv4[qq * 2];
                float4 b = xv4[qq * 2 + 1];
                uint4 wvv;
                wvv.x = f2bf(silu_f(a.x)) | (f2bf(silu_f(a.y)) << 16);
                wvv.y = f2bf(silu_f(a.z)) | (f2bf(silu_f(a.w)) << 16);
                wvv.z = f2bf(silu_f(b.x)) | (f2bf(silu_f(b.y)) << 16);
                wvv.w = f2bf(silu_f(b.z)) | (f2bf(silu_f(b.w)) << 16);
                *reinterpret_cast<uint4*>(&As[r_st * LDSS + half * 32 + qq * 8]) = wvv;
            }
        } else {
            const int i0 = (kc - 4) * 8;
            float4 xv = *reinterpret_cast<const float4*>(
                x + (size_t)(row0 + r_st) * IN_F + i0 + half * 4);
            float xs4[4] = {xv.x, xv.y, xv.z, xv.w};
#pragma unroll
            for (int xi = 0; xi < 4; ++xi) {
                float xx = xs4[xi];
                float u = (xx + 2.2f) * 2.5f;
                float jf = floorf(u);
                float t = u - jf;
                int j0 = (int)jf;
                float t2 = t * t, t3 = t2 * t;
                float p3 = t3 * (1.0f / 6.0f);
                float p2 = -0.5f * t3 + 0.5f * t2 + 0.5f * t + (1.0f / 6.0f);
                float p1 = 0.5f * t3 - t2 + (2.0f / 3.0f);
                float omt = 1.0f - t;
                float p0 = omt * omt * omt * (1.0f / 6.0f);
                uint64_t packed = (uint64_t)f2bf(p0) | ((uint64_t)f2bf(p1) << 16) |
                                  ((uint64_t)f2bf(p2) << 32) | ((uint64_t)f2bf(p3) << 48);
                unsigned __int128 v = 0;
                if ((unsigned)j0 <= 10u) {
                    int sh = j0 * 16 - 48;
                    unsigned __int128 p = (unsigned __int128)packed;
                    v = (sh >= 0) ? (p << sh) : (p >> (-sh));
                }
                uint4 wvv;
                wvv.x = (uint32_t)v;
                wvv.y = (uint32_t)(v >> 32);
                wvv.z = (uint32_t)(v >> 64);
                wvv.w = (uint32_t)(v >> 96);
                *reinterpret_cast<uint4*>(&As[r_st * LDSS + half * 32 + xi * 8]) = wvv;
            }
        }
        __syncthreads();

#pragma unroll
        for (int kk = 0; kk < BK; kk += 32) {
            bf16x8 af[4], bfv[4];
#pragma unroll
            for (int mt = 0; mt < 4; ++mt)
                af[mt] = *reinterpret_cast<const bf16x8*>(
                    &As[(wm * 64 + mt * 16 + l15) * LDSS + kk + q * 8]);
#pragma unroll
            for (int nt = 0; nt < 4; ++nt)
                bfv[nt] = *reinterpret_cast<const bf16x8*>(
                    &Bs[(wn * 64 + nt * 16 + l15) * LDSS + kk + q * 8]);
#pragma unroll
            for (int mt = 0; mt < 4; ++mt)
#pragma unroll
                for (int nt = 0; nt < 4; ++nt)
                    acc[mt][nt] = __builtin_amdgcn_mfma_f32_16x16x32_bf16(
                        af[mt], bfv[nt], acc[mt][nt], 0, 0, 0);
        }
        __syncthreads();
    }

#pragma unroll
    for (int mt = 0; mt < 4; ++mt) {
        int row = row0 + wm * 64 + mt * 16 + q * 4;
#pragma unroll
        for (int nt = 0; nt < 4; ++nt) {
            int col = col0 + wn * 64 + nt * 16 + l15;
#pragma unroll
            for (int r = 0; r < 4; ++r)
                out[(size_t)(row + r) * OUT_F + col] = acc[mt][nt][r];
        }
    }
}

extern "C" void kernel_launch(void* const* d_in, const int* in_sizes, int n_in,
                              void* d_out, int out_size, void* d_ws, size_t ws_size,
                              hipStream_t stream) {
    const float* x  = (const float*)d_in[0];
    const float* bw = (const float*)d_in[1];
    const float* sw = (const float*)d_in[2];
    const float* ss = (const float*)d_in[3];
    unsigned short* Wc = (unsigned short*)d_ws;

    build_w<<<dim3(OUT_F), dim3(IN_F), 0, stream>>>(bw, sw, ss, Wc);

    const int B_ROWS = in_sizes[0] / IN_F;   // 32768

    if (ws_size >= WC_BYTES + AEXP_BYTES) {
        unsigned short* Aexp = (unsigned short*)((char*)d_ws + WC_BYTES);
        expand_a<<<dim3(B_ROWS), dim3(IN_F), 0, stream>>>(x, Aexp);
        kan_gemm2<<<dim3(B_ROWS / 128 * 2), dim3(256), 0, stream>>>(Aexp, Wc, (float*)d_out);
    } else {
        kan_gemm<<<dim3(B_ROWS / 128 * 2), dim3(256), 0, stream>>>(x, Wc, (float*)d_out);
    }
}

// Round 3
// 155.678 us; speedup vs baseline: 1.7606x; 1.0394x over previous
//
#include <hip/hip_runtime.h>
#include <hip/hip_bf16.h>
#include <stdint.h>

// KANLinear, fused single-pass MFMA GEMM with software-pipelined A-expansion.
//   C = A @ W^T,  A (B x 2304) = [silu(x) | cubic-bspline bases(x)] computed on the fly,
//   W (256 x 2304) = [base_weight | spline_weight*scaler] built once in ws (bf16).
// Double-buffered LDS; B staged via global_load_lds DMA (XOR-swizzled, zero-conflict),
// A computed in registers for chunk kc+1 while MFMA runs on chunk kc.

#define IN_F 256
#define OUT_F 256
#define KDIM 2304 /* 256 silu + 256*8 basis */
#define BK 64
#define NCHUNK (KDIM / BK) /* 36 */

#define AS1 __attribute__((address_space(1)))
#define AS3 __attribute__((address_space(3)))

typedef float f32x4 __attribute__((ext_vector_type(4)));
typedef short bf16x8 __attribute__((ext_vector_type(8)));

__device__ __forceinline__ uint32_t f2bf(float f) {
    union { float f; uint32_t u; } c; c.f = f;
    uint32_t u = c.u;
    return (u + 0x7FFFu + ((u >> 16) & 1u)) >> 16;   // RNE
}

__device__ __forceinline__ float silu_f(float v) {
    return v / (1.0f + __expf(-v));
}

// ---------------- kernel 1: combined bf16 weight (OUT_F x KDIM) ----------------
__global__ void build_w(const float* __restrict__ bw, const float* __restrict__ sw,
                        const float* __restrict__ ss, unsigned short* __restrict__ Wc) {
    const int o = blockIdx.x;
    const int i = threadIdx.x;
    Wc[o * KDIM + i] = (unsigned short)f2bf(bw[o * IN_F + i]);
    const float scal = ss[o * IN_F + i];
    const float4* swv = reinterpret_cast<const float4*>(sw + (size_t)(o * IN_F + i) * 8);
    float4 s0 = swv[0], s1 = swv[1];
    uint4 wv;
    wv.x = f2bf(s0.x * scal) | (f2bf(s0.y * scal) << 16);
    wv.y = f2bf(s0.z * scal) | (f2bf(s0.w * scal) << 16);
    wv.z = f2bf(s1.x * scal) | (f2bf(s1.y * scal) << 16);
    wv.w = f2bf(s1.z * scal) | (f2bf(s1.w * scal) << 16);
    *reinterpret_cast<uint4*>(Wc + o * KDIM + IN_F + i * 8) = wv;
}

// ---------------- kernel 2: fused pipelined GEMM ----------------
// LDS layout per tile: addr(row, g) = row*128B + ((g ^ (row&7))*16B), g = k/8
__launch_bounds__(256, 2)
__global__ void kan_fused(const float* __restrict__ x, const unsigned short* __restrict__ Wc,
                          float* __restrict__ out) {
    __shared__ __align__(16) unsigned short As[2][128 * 64];
    __shared__ __align__(16) unsigned short Bs[2][128 * 64];

    const int bid = blockIdx.x;
    const int row0 = (bid >> 1) * 128;
    const int col0 = (bid & 1) * 128;
    const int tid = threadIdx.x;
    const int lane = tid & 63;
    const int w = tid >> 6;            // wave id
    const int wm = w >> 1, wn = w & 1;
    const int l15 = lane & 15;
    const int q = lane >> 4;

    // staging mapping: 8 rows x 8 segments per wave-instruction
    const int sr = lane >> 3;          // row within 8-row group
    const int s  = lane & 7;           // physical 16B segment
    const int g  = s ^ sr;             // logical k-segment held by this thread
    const int srow = w * 32 + sr;      // + j*8 (row&7 == sr)

    f32x4 acc[4][4] = {};
    float xr[4][8];                    // staged x for the next chunk

    auto stage_b = [&](int kc, int buf) {
#pragma unroll
        for (int j = 0; j < 4; ++j) {
            const unsigned short* gp =
                Wc + (size_t)(col0 + srow + j * 8) * KDIM + kc * BK + g * 8;
            __builtin_amdgcn_global_load_lds((const AS1 void*)gp,
                                             (AS3 void*)&Bs[buf][(w * 32 + j * 8) * 64],
                                             16, 0, 0);
        }
    };
    auto load_x = [&](int kc) {
        if (kc < 4) {
            // silu region: this thread covers 8 x values
#pragma unroll
            for (int j = 0; j < 4; ++j) {
                const float* xp = x + (size_t)(row0 + srow + j * 8) * IN_F + kc * 64 + g * 8;
                float4 a = *reinterpret_cast<const float4*>(xp);
                float4 b = *reinterpret_cast<const float4*>(xp + 4);
                xr[j][0] = a.x; xr[j][1] = a.y; xr[j][2] = a.z; xr[j][3] = a.w;
                xr[j][4] = b.x; xr[j][5] = b.y; xr[j][6] = b.z; xr[j][7] = b.w;
            }
        } else {
            // basis region: this thread covers input i0+g (8 coefs from one x)
            const int i0 = (kc - 4) * 8 + g;
#pragma unroll
            for (int j = 0; j < 4; ++j)
                xr[j][0] = x[(size_t)(row0 + srow + j * 8) * IN_F + i0];
        }
    };
    auto write_a = [&](int kc, int buf) {
        if (kc < 4) {
#pragma unroll
            for (int j = 0; j < 4; ++j) {
                uint4 wv;
                wv.x = f2bf(silu_f(xr[j][0])) | (f2bf(silu_f(xr[j][1])) << 16);
                wv.y = f2bf(silu_f(xr[j][2])) | (f2bf(silu_f(xr[j][3])) << 16);
                wv.z = f2bf(silu_f(xr[j][4])) | (f2bf(silu_f(xr[j][5])) << 16);
                wv.w = f2bf(silu_f(xr[j][6])) | (f2bf(silu_f(xr[j][7])) << 16);
                *reinterpret_cast<uint4*>(&As[buf][(srow + j * 8) * 64 + s * 8]) = wv;
            }
        } else {
#pragma unroll
            for (int j = 0; j < 4; ++j) {
                float xx = xr[j][0];
                float u = (xx + 2.2f) * 2.5f;   // (x - grid[0]) / h
                float jf = floorf(u);
                float t = u - jf;
                int j0 = (int)jf;
                float t2 = t * t, t3 = t2 * t;
                float p3 = t3 * (1.0f / 6.0f);                                // j = j0
                float p2 = -0.5f * t3 + 0.5f * t2 + 0.5f * t + (1.0f / 6.0f); // j = j0-1
                float p1 = 0.5f * t3 - t2 + (2.0f / 3.0f);                    // j = j0-2
                float omt = 1.0f - t;
                float p0 = omt * omt * omt * (1.0f / 6.0f);                   // j = j0-3
                uint64_t packed = (uint64_t)f2bf(p0) | ((uint64_t)f2bf(p1) << 16) |
                                  ((uint64_t)f2bf(p2) << 32) | ((uint64_t)f2bf(p3) << 48);
                unsigned __int128 v = 0;
                if ((unsigned)j0 <= 10u) {
                    int sh = j0 * 16 - 48;
                    unsigned __int128 p = (unsigned __int128)packed;
                    v = (sh >= 0) ? (p << sh) : (p >> (-sh));
                }
                uint4 wv;
                wv.x = (uint32_t)v;
                wv.y = (uint32_t)(v >> 32);
                wv.z = (uint32_t)(v >> 64);
                wv.w = (uint32_t)(v >> 96);
                *reinterpret_cast<uint4*>(&As[buf][(srow + j * 8) * 64 + s * 8]) = wv;
            }
        }
    };

    // prologue: stage chunk 0 into buffer 0
    stage_b(0, 0);
    load_x(0);
    write_a(0, 0);
    __syncthreads();

    for (int kc = 0; kc < NCHUNK; ++kc) {
        const int cur = kc & 1;
        const int nxt = cur ^ 1;
        if (kc + 1 < NCHUNK) {
            stage_b(kc + 1, nxt);   // async DMA, drains at the barrier
            load_x(kc + 1);         // latency hidden under the MFMA block
        }
#pragma unroll
        for (int kk = 0; kk < BK; kk += 32) {
            bf16x8 af[4], bfv[4];
            const int g0 = (kk >> 3) + q;
#pragma unroll
            for (int mt = 0; mt < 4; ++mt) {
                int r = wm * 64 + mt * 16 + l15;
                af[mt] = *reinterpret_cast<const bf16x8*>(
                    &As[cur][r * 64 + ((g0 ^ (r & 7)) << 3)]);
            }
#pragma unroll
            for (int nt = 0; nt < 4; ++nt) {
                int r = wn * 64 + nt * 16 + l15;
                bfv[nt] = *reinterpret_cast<const bf16x8*>(
                    &Bs[cur][r * 64 + ((g0 ^ (r & 7)) << 3)]);
            }
#pragma unroll
            for (int mt = 0; mt < 4; ++mt)
#pragma unroll
                for (int nt = 0; nt < 4; ++nt)
                    acc[mt][nt] = __builtin_amdgcn_mfma_f32_16x16x32_bf16(
                        af[mt], bfv[nt], acc[mt][nt], 0, 0, 0);
        }
        if (kc + 1 < NCHUNK) write_a(kc + 1, nxt);
        __syncthreads();
    }

    // epilogue: C/D layout col = lane&15, row = (lane>>4)*4 + reg
#pragma unroll
    for (int mt = 0; mt < 4; ++mt) {
        int row = row0 + wm * 64 + mt * 16 + q * 4;
#pragma unroll
        for (int nt = 0; nt < 4; ++nt) {
            int col = col0 + wn * 64 + nt * 16 + l15;
#pragma unroll
            for (int r = 0; r < 4; ++r)
                out[(size_t)(row + r) * OUT_F + col] = acc[mt][nt][r];
        }
    }
}

extern "C" void kernel_launch(void* const* d_in, const int* in_sizes, int n_in,
                              void* d_out, int out_size, void* d_ws, size_t ws_size,
                              hipStream_t stream) {
    const float* x  = (const float*)d_in[0];
    const float* bw = (const float*)d_in[1];
    const float* sw = (const float*)d_in[2];
    const float* ss = (const float*)d_in[3];
    unsigned short* Wc = (unsigned short*)d_ws;   // 256*2304*2 = 1.18 MB

    build_w<<<dim3(OUT_F), dim3(IN_F), 0, stream>>>(bw, sw, ss, Wc);

    const int B_ROWS = in_sizes[0] / IN_F;        // 32768
    kan_fused<<<dim3(B_ROWS / 128 * 2), dim3(256), 0, stream>>>(x, Wc, (float*)d_out);
}

// Round 4
// 154.359 us; speedup vs baseline: 1.7757x; 1.0085x over previous
//
#include <hip/hip_runtime.h>
#include <hip/hip_bf16.h>
#include <stdint.h>

// KANLinear, fused single-pass MFMA GEMM with software-pipelined A-expansion.
//   C = A @ W^T,  A (B x 2304) = [silu(x) | cubic-bspline bases(x)] computed on the fly,
//   W (256 x 2304) = [base_weight | spline_weight*scaler] built once in ws (bf16).
// R4: basis polynomial eval replaced by a 512-bin lookup table (packed 4xbf16 per
// entry, global/L1-resident) gathered in load_x so latency hides under the MFMAs.

#define IN_F 256
#define OUT_F 256
#define KDIM 2304 /* 256 silu + 256*8 basis */
#define BK 64
#define NCHUNK (KDIM / BK) /* 36 */
#define TBINS 512
#define WC_BYTES ((size_t)OUT_F * KDIM * 2) /* 1,179,648 (8-aligned) */

#define AS1 __attribute__((address_space(1)))
#define AS3 __attribute__((address_space(3)))

typedef float f32x4 __attribute__((ext_vector_type(4)));
typedef short bf16x8 __attribute__((ext_vector_type(8)));

__device__ __forceinline__ uint32_t f2bf(float f) {
    union { float f; uint32_t u; } c; c.f = f;
    uint32_t u = c.u;
    return (u + 0x7FFFu + ((u >> 16) & 1u)) >> 16;   // RNE
}

__device__ __forceinline__ float silu_f(float v) {
    return v / (1.0f + __expf(-v));
}

// ---------------- kernel 1: combined bf16 weight + basis table ----------------
__global__ void build_w(const float* __restrict__ bw, const float* __restrict__ sw,
                        const float* __restrict__ ss, unsigned short* __restrict__ Wc,
                        uint64_t* __restrict__ tg) {
    const int o = blockIdx.x;
    const int i = threadIdx.x;
    Wc[o * KDIM + i] = (unsigned short)f2bf(bw[o * IN_F + i]);
    const float scal = ss[o * IN_F + i];
    const float4* swv = reinterpret_cast<const float4*>(sw + (size_t)(o * IN_F + i) * 8);
    float4 s0 = swv[0], s1 = swv[1];
    uint4 wv;
    wv.x = f2bf(s0.x * scal) | (f2bf(s0.y * scal) << 16);
    wv.y = f2bf(s0.z * scal) | (f2bf(s0.w * scal) << 16);
    wv.z = f2bf(s1.x * scal) | (f2bf(s1.y * scal) << 16);
    wv.w = f2bf(s1.z * scal) | (f2bf(s1.w * scal) << 16);
    *reinterpret_cast<uint4*>(Wc + o * KDIM + IN_F + i * 8) = wv;

    if (o == 0) {
        for (int k = i; k < TBINS; k += IN_F) {
            float t = (k + 0.5f) * (1.0f / TBINS);
            float t2 = t * t, t3 = t2 * t;
            float p3 = t3 * (1.0f / 6.0f);
            float p2 = -0.5f * t3 + 0.5f * t2 + 0.5f * t + (1.0f / 6.0f);
            float p1 = 0.5f * t3 - t2 + (2.0f / 3.0f);
            float omt = 1.0f - t;
            float p0 = omt * omt * omt * (1.0f / 6.0f);
            tg[k] = (uint64_t)f2bf(p0) | ((uint64_t)f2bf(p1) << 16) |
                    ((uint64_t)f2bf(p2) << 32) | ((uint64_t)f2bf(p3) << 48);
        }
    }
}

// ---------------- kernel 2: fused pipelined GEMM ----------------
// LDS layout per tile: addr(row, g) = row*128B + ((g ^ (row&7))*16B), g = k/8
__launch_bounds__(256, 2)
__global__ void kan_fused(const float* __restrict__ x, const unsigned short* __restrict__ Wc,
                          const uint64_t* __restrict__ tg, float* __restrict__ out) {
    __shared__ __align__(16) unsigned short As[2][128 * 64];
    __shared__ __align__(16) unsigned short Bs[2][128 * 64];

    const int bid = blockIdx.x;
    const int row0 = (bid >> 1) * 128;
    const int col0 = (bid & 1) * 128;
    const int tid = threadIdx.x;
    const int lane = tid & 63;
    const int w = tid >> 6;            // wave id
    const int wm = w >> 1, wn = w & 1;
    const int l15 = lane & 15;
    const int q = lane >> 4;

    // staging mapping: 8 rows x 8 segments per wave-instruction
    const int sr = lane >> 3;          // row within 8-row group
    const int s  = lane & 7;           // physical 16B segment
    const int g  = s ^ sr;             // logical k-segment held by this thread
    const int srow = w * 32 + sr;      // + j*8 (row&7 == sr)

    f32x4 acc[4][4] = {};
    float xr[4][8];                    // staged x (silu chunks)
    uint64_t pk4[4];                   // gathered table entries (basis chunks)
    int j04[4];                        // cell indices (basis chunks)

    auto stage_b = [&](int kc, int buf) {
#pragma unroll
        for (int j = 0; j < 4; ++j) {
            const unsigned short* gp =
                Wc + (size_t)(col0 + srow + j * 8) * KDIM + kc * BK + g * 8;
            __builtin_amdgcn_global_load_lds((const AS1 void*)gp,
                                             (AS3 void*)&Bs[buf][(w * 32 + j * 8) * 64],
                                             16, 0, 0);
        }
    };
    auto load_x = [&](int kc) {
        if (kc < 4) {
            // silu region: this thread covers 8 x values
#pragma unroll
            for (int j = 0; j < 4; ++j) {
                const float* xp = x + (size_t)(row0 + srow + j * 8) * IN_F + kc * 64 + g * 8;
                float4 a = *reinterpret_cast<const float4*>(xp);
                float4 b = *reinterpret_cast<const float4*>(xp + 4);
                xr[j][0] = a.x; xr[j][1] = a.y; xr[j][2] = a.z; xr[j][3] = a.w;
                xr[j][4] = b.x; xr[j][5] = b.y; xr[j][6] = b.z; xr[j][7] = b.w;
            }
        } else {
            // basis region: this thread covers input i0+g (8 coefs from one x);
            // issue the dependent table gather NOW so it hides under the MFMA block
            const int i0 = (kc - 4) * 8 + g;
#pragma unroll
            for (int j = 0; j < 4; ++j) {
                float xx = x[(size_t)(row0 + srow + j * 8) * IN_F + i0];
                float u = __builtin_fmaf(xx, 2.5f, 5.5f);   // (x - grid0)/h
                float jf = floorf(u);
                int bin = (int)((u - jf) * (float)TBINS) & (TBINS - 1);
                j04[j] = (int)jf;
                pk4[j] = tg[bin];
            }
        }
    };
    auto write_a = [&](int kc, int buf) {
        if (kc < 4) {
#pragma unroll
            for (int j = 0; j < 4; ++j) {
                uint4 wv;
                wv.x = f2bf(silu_f(xr[j][0])) | (f2bf(silu_f(xr[j][1])) << 16);
                wv.y = f2bf(silu_f(xr[j][2])) | (f2bf(silu_f(xr[j][3])) << 16);
                wv.z = f2bf(silu_f(xr[j][4])) | (f2bf(silu_f(xr[j][5])) << 16);
                wv.w = f2bf(silu_f(xr[j][6])) | (f2bf(silu_f(xr[j][7])) << 16);
                *reinterpret_cast<uint4*>(&As[buf][(srow + j * 8) * 64 + s * 8]) = wv;
            }
        } else {
#pragma unroll
            for (int j = 0; j < 4; ++j) {
                int j0 = j04[j];
                uint64_t pk = ((unsigned)j0 <= 10u) ? pk4[j] : 0ull;
                int jc = j0 < 0 ? 0 : (j0 > 10 ? 10 : j0);   // keep shift amount legal
                int sh = jc * 16 - 48;
                unsigned __int128 v = (unsigned __int128)pk;
                v = (sh >= 0) ? (v << sh) : (v >> (-sh));
                uint4 wv;
                wv.x = (uint32_t)v;
                wv.y = (uint32_t)(v >> 32);
                wv.z = (uint32_t)(v >> 64);
                wv.w = (uint32_t)(v >> 96);
                *reinterpret_cast<uint4*>(&As[buf][(srow + j * 8) * 64 + s * 8]) = wv;
            }
        }
    };

    // prologue: stage chunk 0 into buffer 0
    stage_b(0, 0);
    load_x(0);
    write_a(0, 0);
    __syncthreads();

    for (int kc = 0; kc < NCHUNK; ++kc) {
        const int cur = kc & 1;
        const int nxt = cur ^ 1;
        if (kc + 1 < NCHUNK) {
            stage_b(kc + 1, nxt);   // async DMA, drains at the barrier
            load_x(kc + 1);         // x loads + table gathers hide under the MFMA block
        }
#pragma unroll
        for (int kk = 0; kk < BK; kk += 32) {
            bf16x8 af[4], bfv[4];
            const int g0 = (kk >> 3) + q;
#pragma unroll
            for (int mt = 0; mt < 4; ++mt) {
                int r = wm * 64 + mt * 16 + l15;
                af[mt] = *reinterpret_cast<const bf16x8*>(
                    &As[cur][r * 64 + ((g0 ^ (r & 7)) << 3)]);
            }
#pragma unroll
            for (int nt = 0; nt < 4; ++nt) {
                int r = wn * 64 + nt * 16 + l15;
                bfv[nt] = *reinterpret_cast<const bf16x8*>(
                    &Bs[cur][r * 64 + ((g0 ^ (r & 7)) << 3)]);
            }
#pragma unroll
            for (int mt = 0; mt < 4; ++mt)
#pragma unroll
                for (int nt = 0; nt < 4; ++nt)
                    acc[mt][nt] = __builtin_amdgcn_mfma_f32_16x16x32_bf16(
                        af[mt], bfv[nt], acc[mt][nt], 0, 0, 0);
        }
        if (kc + 1 < NCHUNK) write_a(kc + 1, nxt);
        __syncthreads();
    }

    // epilogue: C/D layout col = lane&15, row = (lane>>4)*4 + reg
#pragma unroll
    for (int mt = 0; mt < 4; ++mt) {
        int row = row0 + wm * 64 + mt * 16 + q * 4;
#pragma unroll
        for (int nt = 0; nt < 4; ++nt) {
            int col = col0 + wn * 64 + nt * 16 + l15;
#pragma unroll
            for (int r = 0; r < 4; ++r)
                out[(size_t)(row + r) * OUT_F + col] = acc[mt][nt][r];
        }
    }
}

extern "C" void kernel_launch(void* const* d_in, const int* in_sizes, int n_in,
                              void* d_out, int out_size, void* d_ws, size_t ws_size,
                              hipStream_t stream) {
    const float* x  = (const float*)d_in[0];
    const float* bw = (const float*)d_in[1];
    const float* sw = (const float*)d_in[2];
    const float* ss = (const float*)d_in[3];
    unsigned short* Wc = (unsigned short*)d_ws;             // 1.18 MB
    uint64_t* tg = (uint64_t*)((char*)d_ws + WC_BYTES);     // 4 KB basis table

    build_w<<<dim3(OUT_F), dim3(IN_F), 0, stream>>>(bw, sw, ss, Wc, tg);

    const int B_ROWS = in_sizes[0] / IN_F;                  // 32768
    kan_fused<<<dim3(B_ROWS / 128 * 2), dim3(256), 0, stream>>>(x, Wc, tg, (float*)d_out);
}

// Round 5
// 146.919 us; speedup vs baseline: 1.8656x; 1.0506x over previous
//
#include <hip/hip_runtime.h>
#include <hip/hip_bf16.h>
#include <stdint.h>

// KANLinear, fused single-pass MFMA GEMM with software-pipelined A-expansion.
//   C = A @ W^T,  A (B x 2304) = [silu(x) | cubic-bspline bases(x)] computed on the fly,
//   W (256 x 2304) = [base_weight | spline_weight*scaler] built once in ws (bf16).
// R5: 512-thread blocks on the 128x128 tile -> 4 waves/SIMD (2x TLP), per-thread
// A-expansion halved. Basis eval via 512-bin packed-bf16 table (global/L1).

#define IN_F 256
#define OUT_F 256
#define KDIM 2304 /* 256 silu + 256*8 basis */
#define BK 64
#define NCHUNK (KDIM / BK) /* 36 */
#define TBINS 512
#define WC_BYTES ((size_t)OUT_F * KDIM * 2) /* 1,179,648 (8-aligned) */

#define AS1 __attribute__((address_space(1)))
#define AS3 __attribute__((address_space(3)))

typedef float f32x4 __attribute__((ext_vector_type(4)));
typedef short bf16x8 __attribute__((ext_vector_type(8)));

__device__ __forceinline__ uint32_t f2bf(float f) {
    union { float f; uint32_t u; } c; c.f = f;
    uint32_t u = c.u;
    return (u + 0x7FFFu + ((u >> 16) & 1u)) >> 16;   // RNE
}

__device__ __forceinline__ float silu_f(float v) {
    return v / (1.0f + __expf(-v));
}

// ---------------- kernel 1: combined bf16 weight + basis table ----------------
__global__ void build_w(const float* __restrict__ bw, const float* __restrict__ sw,
                        const float* __restrict__ ss, unsigned short* __restrict__ Wc,
                        uint64_t* __restrict__ tg) {
    const int o = blockIdx.x;
    const int i = threadIdx.x;
    Wc[o * KDIM + i] = (unsigned short)f2bf(bw[o * IN_F + i]);
    const float scal = ss[o * IN_F + i];
    const float4* swv = reinterpret_cast<const float4*>(sw + (size_t)(o * IN_F + i) * 8);
    float4 s0 = swv[0], s1 = swv[1];
    uint4 wv;
    wv.x = f2bf(s0.x * scal) | (f2bf(s0.y * scal) << 16);
    wv.y = f2bf(s0.z * scal) | (f2bf(s0.w * scal) << 16);
    wv.z = f2bf(s1.x * scal) | (f2bf(s1.y * scal) << 16);
    wv.w = f2bf(s1.z * scal) | (f2bf(s1.w * scal) << 16);
    *reinterpret_cast<uint4*>(Wc + o * KDIM + IN_F + i * 8) = wv;

    if (o == 0) {
        for (int k = i; k < TBINS; k += IN_F) {
            float t = (k + 0.5f) * (1.0f / TBINS);
            float t2 = t * t, t3 = t2 * t;
            float p3 = t3 * (1.0f / 6.0f);
            float p2 = -0.5f * t3 + 0.5f * t2 + 0.5f * t + (1.0f / 6.0f);
            float p1 = 0.5f * t3 - t2 + (2.0f / 3.0f);
            float omt = 1.0f - t;
            float p0 = omt * omt * omt * (1.0f / 6.0f);
            tg[k] = (uint64_t)f2bf(p0) | ((uint64_t)f2bf(p1) << 16) |
                    ((uint64_t)f2bf(p2) << 32) | ((uint64_t)f2bf(p3) << 48);
        }
    }
}

// ---------------- kernel 2: fused pipelined GEMM, 512 threads ----------------
// LDS layout per tile: addr(row, g) = row*128B + ((g ^ (row&7))*16B), g = k/8
__launch_bounds__(512, 4)
__global__ void kan_fused(const float* __restrict__ x, const unsigned short* __restrict__ Wc,
                          const uint64_t* __restrict__ tg, float* __restrict__ out) {
    __shared__ __align__(16) unsigned short As[2][128 * 64];
    __shared__ __align__(16) unsigned short Bs[2][128 * 64];

    const int bid = blockIdx.x;
    const int row0 = (bid >> 1) * 128;
    const int col0 = (bid & 1) * 128;
    const int tid = threadIdx.x;
    const int lane = tid & 63;
    const int w = tid >> 6;            // wave id 0..7
    const int wm = w >> 2;             // 0..1 : 64-row half
    const int wn = w & 3;              // 0..3 : 32-col quarter
    const int l15 = lane & 15;
    const int q = lane >> 4;

    // staging mapping: each wave covers 16 rows (2 instrs of 8 rows x 8 segments)
    const int sr = lane >> 3;          // row within 8-row group
    const int s  = lane & 7;           // physical 16B segment
    const int g  = s ^ sr;             // logical k-segment held by this thread
    const int srow = w * 16 + sr;      // + j*8, j in {0,1}; (row & 7) == sr

    f32x4 acc[4][2] = {};
    float xr[2][8];                    // staged x (silu chunks)
    uint64_t pk2[2];                   // gathered table entries (basis chunks)
    int j02[2];                        // cell indices (basis chunks)

    auto stage_b = [&](int kc, int buf) {
#pragma unroll
        for (int j = 0; j < 2; ++j) {
            const unsigned short* gp =
                Wc + (size_t)(col0 + srow + j * 8) * KDIM + kc * BK + g * 8;
            __builtin_amdgcn_global_load_lds((const AS1 void*)gp,
                                             (AS3 void*)&Bs[buf][(w * 16 + j * 8) * 64],
                                             16, 0, 0);
        }
    };
    auto load_x = [&](int kc) {
        if (kc < 4) {
#pragma unroll
            for (int j = 0; j < 2; ++j) {
                const float* xp = x + (size_t)(row0 + srow + j * 8) * IN_F + kc * 64 + g * 8;
                float4 a = *reinterpret_cast<const float4*>(xp);
                float4 b = *reinterpret_cast<const float4*>(xp + 4);
                xr[j][0] = a.x; xr[j][1] = a.y; xr[j][2] = a.z; xr[j][3] = a.w;
                xr[j][4] = b.x; xr[j][5] = b.y; xr[j][6] = b.z; xr[j][7] = b.w;
            }
        } else {
            // basis region: this thread covers input i0+g for 2 rows; issue the
            // dependent table gather now so it hides under the MFMA block
            const int i0 = (kc - 4) * 8 + g;
#pragma unroll
            for (int j = 0; j < 2; ++j) {
                float xx = x[(size_t)(row0 + srow + j * 8) * IN_F + i0];
                float u = __builtin_fmaf(xx, 2.5f, 5.5f);   // (x - grid0)/h
                float jf = floorf(u);
                int bin = (int)((u - jf) * (float)TBINS) & (TBINS - 1);
                j02[j] = (int)jf;
                pk2[j] = tg[bin];
            }
        }
    };
    auto write_a = [&](int kc, int buf) {
        if (kc < 4) {
#pragma unroll
            for (int j = 0; j < 2; ++j) {
                uint4 wv;
                wv.x = f2bf(silu_f(xr[j][0])) | (f2bf(silu_f(xr[j][1])) << 16);
                wv.y = f2bf(silu_f(xr[j][2])) | (f2bf(silu_f(xr[j][3])) << 16);
                wv.z = f2bf(silu_f(xr[j][4])) | (f2bf(silu_f(xr[j][5])) << 16);
                wv.w = f2bf(silu_f(xr[j][6])) | (f2bf(silu_f(xr[j][7])) << 16);
                *reinterpret_cast<uint4*>(&As[buf][(srow + j * 8) * 64 + s * 8]) = wv;
            }
        } else {
#pragma unroll
            for (int j = 0; j < 2; ++j) {
                int j0 = j02[j];
                uint64_t pk = ((unsigned)j0 <= 10u) ? pk2[j] : 0ull;
                int jc = j0 < 0 ? 0 : (j0 > 10 ? 10 : j0);   // keep shift amount legal
                int sh = jc * 16 - 48;
                unsigned __int128 v = (unsigned __int128)pk;
                v = (sh >= 0) ? (v << sh) : (v >> (-sh));
                uint4 wv;
                wv.x = (uint32_t)v;
                wv.y = (uint32_t)(v >> 32);
                wv.z = (uint32_t)(v >> 64);
                wv.w = (uint32_t)(v >> 96);
                *reinterpret_cast<uint4*>(&As[buf][(srow + j * 8) * 64 + s * 8]) = wv;
            }
        }
    };

    // prologue: stage chunk 0 into buffer 0
    stage_b(0, 0);
    load_x(0);
    write_a(0, 0);
    __syncthreads();

    for (int kc = 0; kc < NCHUNK; ++kc) {
        const int cur = kc & 1;
        const int nxt = cur ^ 1;
        if (kc + 1 < NCHUNK) {
            stage_b(kc + 1, nxt);   // async DMA, drains at the barrier
            load_x(kc + 1);         // x loads + table gathers hide under the MFMA block
        }
#pragma unroll
        for (int kk = 0; kk < BK; kk += 32) {
            bf16x8 af[4], bfv[2];
            const int g0 = (kk >> 3) + q;
#pragma unroll
            for (int mt = 0; mt < 4; ++mt) {
                int r = wm * 64 + mt * 16 + l15;
                af[mt] = *reinterpret_cast<const bf16x8*>(
                    &As[cur][r * 64 + ((g0 ^ (r & 7)) << 3)]);
            }
#pragma unroll
            for (int nt = 0; nt < 2; ++nt) {
                int r = wn * 32 + nt * 16 + l15;
                bfv[nt] = *reinterpret_cast<const bf16x8*>(
                    &Bs[cur][r * 64 + ((g0 ^ (r & 7)) << 3)]);
            }
#pragma unroll
            for (int mt = 0; mt < 4; ++mt)
#pragma unroll
                for (int nt = 0; nt < 2; ++nt)
                    acc[mt][nt] = __builtin_amdgcn_mfma_f32_16x16x32_bf16(
                        af[mt], bfv[nt], acc[mt][nt], 0, 0, 0);
        }
        if (kc + 1 < NCHUNK) write_a(kc + 1, nxt);
        __syncthreads();
    }

    // epilogue: C/D layout col = lane&15, row = (lane>>4)*4 + reg
#pragma unroll
    for (int mt = 0; mt < 4; ++mt) {
        int row = row0 + wm * 64 + mt * 16 + q * 4;
#pragma unroll
        for (int nt = 0; nt < 2; ++nt) {
            int col = col0 + wn * 32 + nt * 16 + l15;
#pragma unroll
            for (int r = 0; r < 4; ++r)
                out[(size_t)(row + r) * OUT_F + col] = acc[mt][nt][r];
        }
    }
}

extern "C" void kernel_launch(void* const* d_in, const int* in_sizes, int n_in,
                              void* d_out, int out_size, void* d_ws, size_t ws_size,
                              hipStream_t stream) {
    const float* x  = (const float*)d_in[0];
    const float* bw = (const float*)d_in[1];
    const float* sw = (const float*)d_in[2];
    const float* ss = (const float*)d_in[3];
    unsigned short* Wc = (unsigned short*)d_ws;             // 1.18 MB
    uint64_t* tg = (uint64_t*)((char*)d_ws + WC_BYTES);     // 4 KB basis table

    build_w<<<dim3(OUT_F), dim3(IN_F), 0, stream>>>(bw, sw, ss, Wc, tg);

    const int B_ROWS = in_sizes[0] / IN_F;                  // 32768
    kan_fused<<<dim3(B_ROWS / 128 * 2), dim3(512), 0, stream>>>(x, Wc, tg, (float*)d_out);
}